// Round 17
// baseline (229.874 us; speedup 1.0000x reference)
//
#include <hip/hip_runtime.h>

#define B_ 4
#define C_ 64
#define H_ 256
#define W_ 256
#define HW_ (H_*W_)
#define MID_ 12
#define NPB_ 1024   // gap partial slots per image (= 4 segs x 256 rows)

__device__ __forceinline__ float wave_reduce64(float v) {
#pragma unroll
    for (int off = 32; off; off >>= 1) v += __shfl_xor(v, off, 64);
    return v;
}

__device__ __forceinline__ void fnorm9(float* t9, const float* __restrict__ sstd) {
    float mean = 0.f;
#pragma unroll
    for (int t = 0; t < 9; ++t) mean += t9[t];
    mean *= (1.f / 9.f);
    float var = 0.f;
#pragma unroll
    for (int t = 0; t < 9; ++t) { float d = t9[t] - mean; var += d * d; }
    float inv = 1.f / (sqrtf(var * (1.f / 8.f)) + 1e-10f);
#pragma unroll
    for (int t = 0; t < 9; ++t) t9[t] = (t9[t] - mean) * inv * sstd[t];
}

// ---------------- prep: read in once -> s + gap partials ----------------
// block = 64-px row segment; 4 waves x 16 channels; lane = 1 px (scalar).
// grid (4, 256, B) = 4096 blocks. Low VGPR + high TLP (apply's recipe).
template<bool HALF>
__global__ __launch_bounds__(256) void prep_kernel(const void* __restrict__ xin,
    const float* __restrict__ sw, const float* __restrict__ sb,
    const float* __restrict__ sstd, float* __restrict__ sarr, float* __restrict__ gp) {
    const int lane = threadIdx.x & 63, wv = threadIdx.x >> 6;
    const int seg = blockIdx.x;           // 0..3
    const int row = blockIdx.y;           // 0..255
    const int b = blockIdx.z;
    const int c0 = wv * 16;
    const int pix = row * W_ + seg * 64 + lane;
    const int bslot = row * 4 + seg;      // 0..NPB_-1
    __shared__ float stl[3][9][64];

    const size_t base = (size_t)b * C_ * HW_ + pix;
    const float* xbF = (const float*)xin + base;
    const _Float16* xbH = (const _Float16*)xin + base;

    // issue all 16 channel loads upfront (independent, scalar, coalesced 256B)
    float v[16];
#pragma unroll
    for (int i = 0; i < 16; ++i) {
        if constexpr (HALF) v[i] = (float)xbH[(size_t)(c0 + i) * HW_];
        else                v[i] = xbF[(size_t)(c0 + i) * HW_];
    }

    float st[9];
#pragma unroll
    for (int t = 0; t < 9; ++t) st[t] = 0.f;

#pragma unroll
    for (int i = 0; i < 16; ++i) {
        const int c = c0 + i;
#pragma unroll
        for (int t = 0; t < 9; ++t) st[t] = fmaf(v[i], sw[t * C_ + c], st[t]);
        float g = wave_reduce64(v[i]);
        if (lane == 0) gp[((size_t)b * C_ + c) * NPB_ + bslot] = g;
    }

    if (wv) {
#pragma unroll
        for (int t = 0; t < 9; ++t) stl[wv - 1][t][lane] = st[t];
    }
    __syncthreads();
    if (wv == 0) {
#pragma unroll
        for (int t = 0; t < 9; ++t)
            st[t] += sb[t] + stl[0][t][lane] + stl[1][t][lane] + stl[2][t][lane];
        fnorm9(st, sstd);
        float* sp = sarr + ((size_t)b * 9) * HW_ + pix;
#pragma unroll
        for (int t = 0; t < 9; ++t) sp[(size_t)t * HW_] = st[t];
    }
}

// ------ cfk: reduce gap partials + SE MLP + FilterNorm -> cf (B,C,12 padded) ------
__global__ __launch_bounds__(256) void cfk(const float* __restrict__ gp,
    const float* __restrict__ cw1, const float* __restrict__ cb1,
    const float* __restrict__ cw2, const float* __restrict__ cb2,
    const float* __restrict__ cstd, float* __restrict__ cf) {
    const int tid = threadIdx.x;
    const int b = tid >> 6, c = tid & 63;
    __shared__ float gsm[B_][C_];
    __shared__ float hsm[B_][MID_];
    {
        const float4* p4 = (const float4*)(gp + ((size_t)b * C_ + c) * NPB_);
        float s = 0.f;
#pragma unroll 8
        for (int i = 0; i < NPB_ / 4; ++i) { float4 v = p4[i]; s += (v.x + v.y) + (v.z + v.w); }
        gsm[b][c] = s * (1.f / HW_);
    }
    __syncthreads();
    if (tid < B_ * MID_) {
        int b2 = tid / MID_, m = tid % MID_;
        float a = cb1[m];
        for (int cc = 0; cc < C_; ++cc) a = fmaf(gsm[b2][cc], cw1[m * C_ + cc], a);
        hsm[b2][m] = fmaxf(a, 0.f);
    }
    __syncthreads();
    float v[9];
    float mean = 0.f;
#pragma unroll
    for (int t = 0; t < 9; ++t) {
        int o = c * 9 + t;
        float a = cb2[o];
#pragma unroll
        for (int m = 0; m < MID_; ++m) a = fmaf(hsm[b][m], cw2[o * MID_ + m], a);
        v[t] = a;
        mean += a;
    }
    mean *= (1.f / 9.f);
    float var = 0.f;
#pragma unroll
    for (int t = 0; t < 9; ++t) { float d = v[t] - mean; var += d * d; }
    float inv = 1.f / (sqrtf(var * (1.f / 8.f)) + 1e-10f);
    float* o12 = cf + ((size_t)b * C_ + c) * 12;
#pragma unroll
    for (int t = 0; t < 9; ++t) o12[t] = (v[t] - mean) * inv * cstd[c * 9 + t];
    o12[9] = 0.f; o12[10] = 0.f; o12[11] = 0.f;
}

// ---------- apply: pure channel-parallel 3x3 dynamic filter (r15 structure) ----------
// block = 64x4 px tile, 8 channels; 1 px/thread; grid (W/64, H/4, B*8) = 8192.
template<bool RELU, bool RESID, bool INH, bool OUTH>
__global__ __launch_bounds__(256) void apply_kernel(const void* __restrict__ in,
    const float* __restrict__ sarr, const float* __restrict__ cf,
    const float* __restrict__ resid, void* __restrict__ out) {
    const int lane = threadIdx.x & 63, wv = threadIdx.x >> 6;
    const int col = blockIdx.x * 64 + lane;
    const int row = blockIdx.y * 4 + wv;
    const int z = blockIdx.z;
    const int b = z >> 3;
    const int c0 = (z & 7) * 8;
    const int pix = row * W_ + col;

    // s taps at my pixel; fold ALL edge masking here
    float s0[9];
    int off9[9];
    {
        const float* sp = sarr + ((size_t)b * 9) * HW_ + pix;
#pragma unroll
        for (int t = 0; t < 9; ++t) s0[t] = sp[(size_t)t * HW_];
#pragma unroll
        for (int dr = -1; dr <= 1; ++dr)
#pragma unroll
            for (int dc = -1; dc <= 1; ++dc) {
                const int t = (dr + 1) * 3 + (dc + 1);
                const bool ok = (row + dr >= 0) && (row + dr < H_) &&
                                (col + dc >= 0) && (col + dc < W_);
                off9[t] = ok ? (pix + dr * W_ + dc) : pix;
                if (!ok) s0[t] = 0.f;
            }
    }

    const size_t cbase = ((size_t)b * C_ + c0) * HW_;
    const float* inF = (const float*)in + cbase;
    const _Float16* inH = (const _Float16*)in + cbase;
    const float* cfb = cf + ((size_t)b * C_ + c0) * 12;
    const float* rb  = RESID ? ((const float*)resid + cbase + pix) : nullptr;
    float* outF = (float*)out + cbase + pix;
    _Float16* outH = (_Float16*)out + cbase + pix;

    float mA[9], mB[9], rAv = 0.f, rBv = 0.f;

#define LD9(M, RV, cc) do {                                                  \
        if constexpr (INH) {                                                 \
            const _Float16* p_ = inH + (size_t)(cc) * HW_;                   \
            _Pragma("unroll")                                                \
            for (int t_ = 0; t_ < 9; ++t_) M[t_] = (float)p_[off9[t_]];      \
        } else {                                                             \
            const float* p_ = inF + (size_t)(cc) * HW_;                      \
            _Pragma("unroll")                                                \
            for (int t_ = 0; t_ < 9; ++t_) M[t_] = p_[off9[t_]];             \
        }                                                                    \
        if (RESID) RV = rb[(size_t)(cc) * HW_];                              \
    } while (0)

#define CP9(M, RV, cc) do {                                                  \
        const float* cfc_ = cfb + (size_t)(cc) * 12;                         \
        float acc_ = 0.f;                                                    \
        _Pragma("unroll")                                                    \
        for (int t_ = 0; t_ < 9; ++t_)                                       \
            acc_ = fmaf(M[t_] * s0[t_], cfc_[t_], acc_);                     \
        float o_ = RELU ? fmaxf(acc_, 0.f) : acc_;                           \
        if (RESID) o_ += RV;                                                 \
        if constexpr (OUTH) outH[(size_t)(cc) * HW_] = (_Float16)o_;         \
        else                outF[(size_t)(cc) * HW_] = o_;                   \
    } while (0)

    LD9(mA, rAv, 0);
#pragma unroll
    for (int c = 0; c < 8; c += 2) {
        LD9(mB, rBv, c + 1);
        CP9(mA, rAv, c);
        if (c + 2 < 8) LD9(mA, rAv, c + 2);
        CP9(mB, rBv, c + 1);
    }
#undef LD9
#undef CP9
}

extern "C" void kernel_launch(void* const* d_in, const int* in_sizes, int n_in,
                              void* d_out, int out_size, void* d_ws, size_t ws_size,
                              hipStream_t stream) {
    const float* x     = (const float*)d_in[0];
    const float* sw1   = (const float*)d_in[1];
    const float* sb1   = (const float*)d_in[2];
    const float* sstd1 = (const float*)d_in[3];
    const float* cw1_1 = (const float*)d_in[4];
    const float* cb1_1 = (const float*)d_in[5];
    const float* cw2_1 = (const float*)d_in[6];
    const float* cb2_1 = (const float*)d_in[7];
    const float* cstd1 = (const float*)d_in[8];
    const float* sw2   = (const float*)d_in[9];
    const float* sb2   = (const float*)d_in[10];
    const float* sstd2 = (const float*)d_in[11];
    const float* cw1_2 = (const float*)d_in[12];
    const float* cb1_2 = (const float*)d_in[13];
    const float* cw2_2 = (const float*)d_in[14];
    const float* cb2_2 = (const float*)d_in[15];
    const float* cstd2 = (const float*)d_in[16];
    float* outp = (float*)d_out;

    const size_t n_out1 = (size_t)B_ * C_ * HW_;     // 16,777,216 (fp16)
    const size_t n_s    = (size_t)B_ * 9 * HW_;      // 2,359,296
    const size_t n_cf   = (size_t)B_ * C_ * 12;      // 3,072 (padded)
    const size_t n_gp   = (size_t)B_ * C_ * NPB_;    // 262,144
    const size_t need = n_out1 * sizeof(_Float16)
                      + (2 * n_s + 2 * n_cf + 2 * n_gp) * sizeof(float);
    if (ws_size < need) return;

    _Float16* out1h = (_Float16*)d_ws;
    float* s1  = (float*)((char*)d_ws + n_out1 * sizeof(_Float16));
    float* s2  = s1 + n_s;
    float* cf1 = s2 + n_s;
    float* cf2 = cf1 + n_cf;
    float* gp1 = cf2 + n_cf;
    float* gp2 = gp1 + n_gp;

    dim3 gprep(4, H_, B_);                  // 4096 blocks, 64-px segment each
    dim3 gapply(W_ / 64, H_ / 4, B_ * 8);   // 8192 blocks, 8 ch each

    // pass 1
    prep_kernel<false><<<gprep, 256, 0, stream>>>(x, sw1, sb1, sstd1, s1, gp1);
    cfk<<<1, 256, 0, stream>>>(gp1, cw1_1, cb1_1, cw2_1, cb2_1, cstd1, cf1);
    apply_kernel<true, false, false, true><<<gapply, 256, 0, stream>>>(
        x, s1, cf1, nullptr, out1h);
    // pass 2
    prep_kernel<true><<<gprep, 256, 0, stream>>>(out1h, sw2, sb2, sstd2, s2, gp2);
    cfk<<<1, 256, 0, stream>>>(gp2, cw1_2, cb1_2, cw2_2, cb2_2, cstd2, cf2);
    apply_kernel<false, true, true, false><<<gapply, 256, 0, stream>>>(
        out1h, s2, cf2, x, outp);
}

// Round 18
// 162.892 us; speedup vs baseline: 1.4112x; 1.4112x over previous
//
#include <hip/hip_runtime.h>

#define B_ 4
#define C_ 64
#define H_ 256
#define W_ 256
#define HW_ (H_*W_)
#define MID_ 12
#define NPB1 256    // gap partial slots, pass 1 (prep1: one per row-block)
#define NPB2 1024   // gap partial slots, pass 2 (apply1: 256 tiles x 4 waves)

typedef _Float16 h4 __attribute__((ext_vector_type(4)));

__device__ __forceinline__ float wave_reduce64(float v) {
#pragma unroll
    for (int off = 32; off; off >>= 1) v += __shfl_xor(v, off, 64);
    return v;
}

// FilterNorm over 9 taps, vectorized over 4 px; writes to sp (stride HW_)
__device__ __forceinline__ void fnorm4_store(const float4* t9,
    const float* __restrict__ sstd, float* sp) {
    float4 mean = make_float4(0, 0, 0, 0);
#pragma unroll
    for (int t = 0; t < 9; ++t) {
        mean.x += t9[t].x; mean.y += t9[t].y; mean.z += t9[t].z; mean.w += t9[t].w;
    }
    mean.x *= (1.f/9.f); mean.y *= (1.f/9.f); mean.z *= (1.f/9.f); mean.w *= (1.f/9.f);
    float4 var = make_float4(0, 0, 0, 0);
#pragma unroll
    for (int t = 0; t < 9; ++t) {
        float dx = t9[t].x - mean.x, dy = t9[t].y - mean.y;
        float dz = t9[t].z - mean.z, dw = t9[t].w - mean.w;
        var.x = fmaf(dx, dx, var.x); var.y = fmaf(dy, dy, var.y);
        var.z = fmaf(dz, dz, var.z); var.w = fmaf(dw, dw, var.w);
    }
    float ix = 1.f / (sqrtf(var.x * (1.f/8.f)) + 1e-10f);
    float iy = 1.f / (sqrtf(var.y * (1.f/8.f)) + 1e-10f);
    float iz = 1.f / (sqrtf(var.z * (1.f/8.f)) + 1e-10f);
    float iw = 1.f / (sqrtf(var.w * (1.f/8.f)) + 1e-10f);
#pragma unroll
    for (int t = 0; t < 9; ++t) {
        float sd = sstd[t];
        *(float4*)(sp + (size_t)t * HW_) = make_float4(
            (t9[t].x - mean.x) * ix * sd, (t9[t].y - mean.y) * iy * sd,
            (t9[t].z - mean.z) * iz * sd, (t9[t].w - mean.w) * iw * sd);
    }
}

// ---------------- prep: read in once -> s + (optional) gap partials ----------------
// block = 1 row, 4 waves x 16 channels; lane = 4 px. grid (H, B). (r15 structure)
template<bool HALF, bool GAP>
__global__ __launch_bounds__(256) void prep_kernel(const void* __restrict__ xin,
    const float* __restrict__ sw, const float* __restrict__ sb,
    const float* __restrict__ sstd, float* __restrict__ sarr, float* __restrict__ gp) {
    const int lane = threadIdx.x & 63, wv = threadIdx.x >> 6;
    const int row = blockIdx.x;
    const int b = blockIdx.y;
    const int c0 = wv * 16;
    const int pix = row * W_ + lane * 4;
    __shared__ float4 stl[3][9][64];

    float4 st[9];
#pragma unroll
    for (int t = 0; t < 9; ++t) st[t] = make_float4(0, 0, 0, 0);

    const size_t base = (size_t)b * C_ * HW_ + pix;
    const float* xbF = (const float*)xin + base;
    const _Float16* xbH = (const _Float16*)xin + base;

#define LOAD4(DST, CC) do {                                                   \
        if constexpr (HALF) {                                                 \
            h4 v_ = *(const h4*)(xbH + (size_t)(CC) * HW_);                   \
            DST = make_float4((float)v_[0], (float)v_[1],                     \
                              (float)v_[2], (float)v_[3]);                    \
        } else {                                                              \
            DST = *(const float4*)(xbF + (size_t)(CC) * HW_);                 \
        }                                                                     \
    } while (0)

#define PREP_COMP(BUF, CC) do {                                               \
        _Pragma("unroll")                                                     \
        for (int i_ = 0; i_ < 4; ++i_) {                                      \
            const int c_ = (CC) + i_;                                         \
            float4 v_ = BUF[i_];                                              \
            _Pragma("unroll")                                                 \
            for (int t_ = 0; t_ < 9; ++t_) {                                  \
                const float wt_ = sw[t_ * C_ + c_];                           \
                st[t_].x = fmaf(v_.x, wt_, st[t_].x);                         \
                st[t_].y = fmaf(v_.y, wt_, st[t_].y);                         \
                st[t_].z = fmaf(v_.z, wt_, st[t_].z);                         \
                st[t_].w = fmaf(v_.w, wt_, st[t_].w);                         \
            }                                                                 \
            if constexpr (GAP) {                                              \
                float g_ = wave_reduce64(((v_.x + v_.y) + (v_.z + v_.w)));    \
                if (lane == 0)                                                \
                    gp[((size_t)b * C_ + c_) * NPB1 + blockIdx.x] = g_;       \
            }                                                                 \
        }                                                                     \
    } while (0)

    float4 vA[4], vB[4];
#pragma unroll
    for (int i = 0; i < 4; ++i) LOAD4(vA[i], c0 + i);
#pragma unroll
    for (int k = 0; k < 16; k += 8) {
#pragma unroll
        for (int i = 0; i < 4; ++i) LOAD4(vB[i], c0 + k + 4 + i);
        PREP_COMP(vA, c0 + k);
        if (k + 8 < 16) {
#pragma unroll
            for (int i = 0; i < 4; ++i) LOAD4(vA[i], c0 + k + 8 + i);
        }
        PREP_COMP(vB, c0 + k + 4);
    }
#undef LOAD4
#undef PREP_COMP

    if (wv) {
#pragma unroll
        for (int t = 0; t < 9; ++t) stl[wv - 1][t][lane] = st[t];
    }
    __syncthreads();
    if (wv == 0) {
#pragma unroll
        for (int t = 0; t < 9; ++t) {
            float bb = sb[t];
#pragma unroll
            for (int j = 0; j < 3; ++j) {
                float4 o = stl[j][t][lane];
                st[t].x += o.x; st[t].y += o.y; st[t].z += o.z; st[t].w += o.w;
            }
            st[t].x += bb; st[t].y += bb; st[t].z += bb; st[t].w += bb;
        }
        fnorm4_store(st, sstd, sarr + ((size_t)b * 9) * HW_ + pix);
    }
}

// ------ cfk: reduce gap partials + SE MLP + FilterNorm -> cf (B,C,12 padded) ------
template<int NPB>
__global__ __launch_bounds__(256) void cfk(const float* __restrict__ gp,
    const float* __restrict__ cw1, const float* __restrict__ cb1,
    const float* __restrict__ cw2, const float* __restrict__ cb2,
    const float* __restrict__ cstd, float* __restrict__ cf) {
    const int tid = threadIdx.x;
    const int b = tid >> 6, c = tid & 63;
    __shared__ float gsm[B_][C_];
    __shared__ float hsm[B_][MID_];
    {
        const float4* p4 = (const float4*)(gp + ((size_t)b * C_ + c) * NPB);
        float s = 0.f;
#pragma unroll 8
        for (int i = 0; i < NPB / 4; ++i) { float4 v = p4[i]; s += (v.x + v.y) + (v.z + v.w); }
        gsm[b][c] = s * (1.f / HW_);
    }
    __syncthreads();
    if (tid < B_ * MID_) {
        int b2 = tid / MID_, m = tid % MID_;
        float a = cb1[m];
        for (int cc = 0; cc < C_; ++cc) a = fmaf(gsm[b2][cc], cw1[m * C_ + cc], a);
        hsm[b2][m] = fmaxf(a, 0.f);
    }
    __syncthreads();
    float v[9];
    float mean = 0.f;
#pragma unroll
    for (int t = 0; t < 9; ++t) {
        int o = c * 9 + t;
        float a = cb2[o];
#pragma unroll
        for (int m = 0; m < MID_; ++m) a = fmaf(hsm[b][m], cw2[o * MID_ + m], a);
        v[t] = a;
        mean += a;
    }
    mean *= (1.f / 9.f);
    float var = 0.f;
#pragma unroll
    for (int t = 0; t < 9; ++t) { float d = v[t] - mean; var += d * d; }
    float inv = 1.f / (sqrtf(var * (1.f / 8.f)) + 1e-10f);
    float* o12 = cf + ((size_t)b * C_ + c) * 12;
#pragma unroll
    for (int t = 0; t < 9; ++t) o12[t] = (v[t] - mean) * inv * cstd[c * 9 + t];
    o12[9] = 0.f; o12[10] = 0.f; o12[11] = 0.f;
}

// ---------- apply: pure channel-parallel 3x3 dynamic filter (r15 structure) ----------
// block = 64x4 px tile, 8 channels; 1 px/thread; grid (W/64, H/4, B*8) = 8192.
// GAPOUT: also emit per-(tile,wave) GAP partials of the outputs (pre-rounding).
template<bool RELU, bool RESID, bool INH, bool OUTH, bool GAPOUT>
__global__ __launch_bounds__(256) void apply_kernel(const void* __restrict__ in,
    const float* __restrict__ sarr, const float* __restrict__ cf,
    const float* __restrict__ resid, void* __restrict__ out, float* __restrict__ gpn) {
    const int lane = threadIdx.x & 63, wv = threadIdx.x >> 6;
    const int col = blockIdx.x * 64 + lane;
    const int row = blockIdx.y * 4 + wv;
    const int z = blockIdx.z;
    const int b = z >> 3;
    const int c0 = (z & 7) * 8;
    const int pix = row * W_ + col;
    const int gslot = GAPOUT ? (((blockIdx.y * 4 + blockIdx.x) << 2) | wv) : 0;

    // s taps at my pixel; fold ALL edge masking here
    float s0[9];
    int off9[9];
    {
        const float* sp = sarr + ((size_t)b * 9) * HW_ + pix;
#pragma unroll
        for (int t = 0; t < 9; ++t) s0[t] = sp[(size_t)t * HW_];
#pragma unroll
        for (int dr = -1; dr <= 1; ++dr)
#pragma unroll
            for (int dc = -1; dc <= 1; ++dc) {
                const int t = (dr + 1) * 3 + (dc + 1);
                const bool ok = (row + dr >= 0) && (row + dr < H_) &&
                                (col + dc >= 0) && (col + dc < W_);
                off9[t] = ok ? (pix + dr * W_ + dc) : pix;
                if (!ok) s0[t] = 0.f;
            }
    }

    const size_t cbase = ((size_t)b * C_ + c0) * HW_;
    const float* inF = (const float*)in + cbase;
    const _Float16* inH = (const _Float16*)in + cbase;
    const float* cfb = cf + ((size_t)b * C_ + c0) * 12;
    const float* rb  = RESID ? ((const float*)resid + cbase + pix) : nullptr;
    float* outF = (float*)out + cbase + pix;
    _Float16* outH = (_Float16*)out + cbase + pix;

    float mA[9], mB[9], rAv = 0.f, rBv = 0.f;

#define LD9(M, RV, cc) do {                                                  \
        if constexpr (INH) {                                                 \
            const _Float16* p_ = inH + (size_t)(cc) * HW_;                   \
            _Pragma("unroll")                                                \
            for (int t_ = 0; t_ < 9; ++t_) M[t_] = (float)p_[off9[t_]];      \
        } else {                                                             \
            const float* p_ = inF + (size_t)(cc) * HW_;                      \
            _Pragma("unroll")                                                \
            for (int t_ = 0; t_ < 9; ++t_) M[t_] = p_[off9[t_]];             \
        }                                                                    \
        if (RESID) RV = rb[(size_t)(cc) * HW_];                              \
    } while (0)

#define CP9(M, RV, cc) do {                                                  \
        const float* cfc_ = cfb + (size_t)(cc) * 12;                         \
        float acc_ = 0.f;                                                    \
        _Pragma("unroll")                                                    \
        for (int t_ = 0; t_ < 9; ++t_)                                       \
            acc_ = fmaf(M[t_] * s0[t_], cfc_[t_], acc_);                     \
        float o_ = RELU ? fmaxf(acc_, 0.f) : acc_;                           \
        if (RESID) o_ += RV;                                                 \
        if constexpr (GAPOUT) {                                              \
            float g_ = wave_reduce64(o_);                                    \
            if (lane == 0)                                                   \
                gpn[((size_t)b * C_ + c0 + (cc)) * NPB2 + gslot] = g_;       \
        }                                                                    \
        if constexpr (OUTH) outH[(size_t)(cc) * HW_] = (_Float16)o_;         \
        else                outF[(size_t)(cc) * HW_] = o_;                   \
    } while (0)

    LD9(mA, rAv, 0);
#pragma unroll
    for (int c = 0; c < 8; c += 2) {
        LD9(mB, rBv, c + 1);
        CP9(mA, rAv, c);
        if (c + 2 < 8) LD9(mA, rAv, c + 2);
        CP9(mB, rBv, c + 1);
    }
#undef LD9
#undef CP9
}

extern "C" void kernel_launch(void* const* d_in, const int* in_sizes, int n_in,
                              void* d_out, int out_size, void* d_ws, size_t ws_size,
                              hipStream_t stream) {
    const float* x     = (const float*)d_in[0];
    const float* sw1   = (const float*)d_in[1];
    const float* sb1   = (const float*)d_in[2];
    const float* sstd1 = (const float*)d_in[3];
    const float* cw1_1 = (const float*)d_in[4];
    const float* cb1_1 = (const float*)d_in[5];
    const float* cw2_1 = (const float*)d_in[6];
    const float* cb2_1 = (const float*)d_in[7];
    const float* cstd1 = (const float*)d_in[8];
    const float* sw2   = (const float*)d_in[9];
    const float* sb2   = (const float*)d_in[10];
    const float* sstd2 = (const float*)d_in[11];
    const float* cw1_2 = (const float*)d_in[12];
    const float* cb1_2 = (const float*)d_in[13];
    const float* cw2_2 = (const float*)d_in[14];
    const float* cb2_2 = (const float*)d_in[15];
    const float* cstd2 = (const float*)d_in[16];
    float* outp = (float*)d_out;

    const size_t n_out1 = (size_t)B_ * C_ * HW_;     // 16,777,216 (fp16)
    const size_t n_s    = (size_t)B_ * 9 * HW_;      // 2,359,296
    const size_t n_cf   = (size_t)B_ * C_ * 12;      // 3,072 (padded)
    const size_t n_gp1  = (size_t)B_ * C_ * NPB1;    // 65,536
    const size_t n_gp2  = (size_t)B_ * C_ * NPB2;    // 262,144
    const size_t need = n_out1 * sizeof(_Float16)
                      + (2 * n_s + 2 * n_cf + n_gp1 + n_gp2) * sizeof(float);
    if (ws_size < need) return;

    _Float16* out1h = (_Float16*)d_ws;
    float* s1  = (float*)((char*)d_ws + n_out1 * sizeof(_Float16));
    float* s2  = s1 + n_s;
    float* cf1 = s2 + n_s;
    float* cf2 = cf1 + n_cf;
    float* gp1 = cf2 + n_cf;
    float* gp2 = gp1 + n_gp1;

    dim3 gprep(H_, B_);                     // 1024 blocks
    dim3 gapply(W_ / 64, H_ / 4, B_ * 8);   // 8192 blocks, 8 ch each

    // pass 1
    prep_kernel<false, true><<<gprep, 256, 0, stream>>>(x, sw1, sb1, sstd1, s1, gp1);
    cfk<NPB1><<<1, 256, 0, stream>>>(gp1, cw1_1, cb1_1, cw2_1, cb2_1, cstd1, cf1);
    apply_kernel<true, false, false, true, true><<<gapply, 256, 0, stream>>>(
        x, s1, cf1, nullptr, out1h, gp2);
    // pass 2 (prep2: s2 only, no GAP — gap2 came from apply1)
    prep_kernel<true, false><<<gprep, 256, 0, stream>>>(out1h, sw2, sb2, sstd2, s2, nullptr);
    cfk<NPB2><<<1, 256, 0, stream>>>(gp2, cw1_2, cb1_2, cw2_2, cb2_2, cstd2, cf2);
    apply_kernel<false, true, true, false, false><<<gapply, 256, 0, stream>>>(
        out1h, s2, cf2, x, outp, nullptr);
}

// Round 19
// 162.389 us; speedup vs baseline: 1.4156x; 1.0031x over previous
//
#include <hip/hip_runtime.h>

#define B_ 4
#define C_ 64
#define H_ 256
#define W_ 256
#define HW_ (H_*W_)
#define MID_ 12
#define NPB_ 256   // gap partial slots per image (= one per row)

typedef _Float16 h4 __attribute__((ext_vector_type(4)));
typedef _Float16 h2 __attribute__((ext_vector_type(2)));

__device__ __forceinline__ float wave_reduce64(float v) {
#pragma unroll
    for (int off = 32; off; off >>= 1) v += __shfl_xor(v, off, 64);
    return v;
}

// FilterNorm over 9 taps, vectorized over 4 px; writes to sp (stride HW_)
__device__ __forceinline__ void fnorm4_store(const float4* t9,
    const float* __restrict__ sstd, float* sp) {
    float4 mean = make_float4(0, 0, 0, 0);
#pragma unroll
    for (int t = 0; t < 9; ++t) {
        mean.x += t9[t].x; mean.y += t9[t].y; mean.z += t9[t].z; mean.w += t9[t].w;
    }
    mean.x *= (1.f/9.f); mean.y *= (1.f/9.f); mean.z *= (1.f/9.f); mean.w *= (1.f/9.f);
    float4 var = make_float4(0, 0, 0, 0);
#pragma unroll
    for (int t = 0; t < 9; ++t) {
        float dx = t9[t].x - mean.x, dy = t9[t].y - mean.y;
        float dz = t9[t].z - mean.z, dw = t9[t].w - mean.w;
        var.x = fmaf(dx, dx, var.x); var.y = fmaf(dy, dy, var.y);
        var.z = fmaf(dz, dz, var.z); var.w = fmaf(dw, dw, var.w);
    }
    float ix = 1.f / (sqrtf(var.x * (1.f/8.f)) + 1e-10f);
    float iy = 1.f / (sqrtf(var.y * (1.f/8.f)) + 1e-10f);
    float iz = 1.f / (sqrtf(var.z * (1.f/8.f)) + 1e-10f);
    float iw = 1.f / (sqrtf(var.w * (1.f/8.f)) + 1e-10f);
#pragma unroll
    for (int t = 0; t < 9; ++t) {
        float sd = sstd[t];
        *(float4*)(sp + (size_t)t * HW_) = make_float4(
            (t9[t].x - mean.x) * ix * sd, (t9[t].y - mean.y) * iy * sd,
            (t9[t].z - mean.z) * iz * sd, (t9[t].w - mean.w) * iw * sd);
    }
}

// ---------------- prep: read in once -> s + gap partials (r15 structure) ----------------
// block = 1 row, 4 waves x 16 channels; lane = 4 px. grid (H, B).
template<bool HALF>
__global__ __launch_bounds__(256) void prep_kernel(const void* __restrict__ xin,
    const float* __restrict__ sw, const float* __restrict__ sb,
    const float* __restrict__ sstd, float* __restrict__ sarr, float* __restrict__ gp) {
    const int lane = threadIdx.x & 63, wv = threadIdx.x >> 6;
    const int row = blockIdx.x;
    const int b = blockIdx.y;
    const int c0 = wv * 16;
    const int pix = row * W_ + lane * 4;
    __shared__ float4 stl[3][9][64];

    float4 st[9];
#pragma unroll
    for (int t = 0; t < 9; ++t) st[t] = make_float4(0, 0, 0, 0);

    const size_t base = (size_t)b * C_ * HW_ + pix;
    const float* xbF = (const float*)xin + base;
    const _Float16* xbH = (const _Float16*)xin + base;

#define LOAD4(DST, CC) do {                                                   \
        if constexpr (HALF) {                                                 \
            h4 v_ = *(const h4*)(xbH + (size_t)(CC) * HW_);                   \
            DST = make_float4((float)v_[0], (float)v_[1],                     \
                              (float)v_[2], (float)v_[3]);                    \
        } else {                                                              \
            DST = *(const float4*)(xbF + (size_t)(CC) * HW_);                 \
        }                                                                     \
    } while (0)

#define PREP_COMP(BUF, CC) do {                                               \
        _Pragma("unroll")                                                     \
        for (int i_ = 0; i_ < 4; ++i_) {                                      \
            const int c_ = (CC) + i_;                                         \
            float4 v_ = BUF[i_];                                              \
            _Pragma("unroll")                                                 \
            for (int t_ = 0; t_ < 9; ++t_) {                                  \
                const float wt_ = sw[t_ * C_ + c_];                           \
                st[t_].x = fmaf(v_.x, wt_, st[t_].x);                         \
                st[t_].y = fmaf(v_.y, wt_, st[t_].y);                         \
                st[t_].z = fmaf(v_.z, wt_, st[t_].z);                         \
                st[t_].w = fmaf(v_.w, wt_, st[t_].w);                         \
            }                                                                 \
            float g_ = wave_reduce64(((v_.x + v_.y) + (v_.z + v_.w)));        \
            if (lane == 0) gp[((size_t)b * C_ + c_) * NPB_ + blockIdx.x] = g_; \
        }                                                                     \
    } while (0)

    float4 vA[4], vB[4];
#pragma unroll
    for (int i = 0; i < 4; ++i) LOAD4(vA[i], c0 + i);
#pragma unroll
    for (int k = 0; k < 16; k += 8) {
#pragma unroll
        for (int i = 0; i < 4; ++i) LOAD4(vB[i], c0 + k + 4 + i);
        PREP_COMP(vA, c0 + k);
        if (k + 8 < 16) {
#pragma unroll
            for (int i = 0; i < 4; ++i) LOAD4(vA[i], c0 + k + 8 + i);
        }
        PREP_COMP(vB, c0 + k + 4);
    }
#undef LOAD4
#undef PREP_COMP

    if (wv) {
#pragma unroll
        for (int t = 0; t < 9; ++t) stl[wv - 1][t][lane] = st[t];
    }
    __syncthreads();
    if (wv == 0) {
#pragma unroll
        for (int t = 0; t < 9; ++t) {
            float bb = sb[t];
#pragma unroll
            for (int j = 0; j < 3; ++j) {
                float4 o = stl[j][t][lane];
                st[t].x += o.x; st[t].y += o.y; st[t].z += o.z; st[t].w += o.w;
            }
            st[t].x += bb; st[t].y += bb; st[t].z += bb; st[t].w += bb;
        }
        fnorm4_store(st, sstd, sarr + ((size_t)b * 9) * HW_ + pix);
    }
}

// ------ cfk: reduce gap partials + SE MLP + FilterNorm -> cf (B,C,12 padded) ------
__global__ __launch_bounds__(256) void cfk(const float* __restrict__ gp,
    const float* __restrict__ cw1, const float* __restrict__ cb1,
    const float* __restrict__ cw2, const float* __restrict__ cb2,
    const float* __restrict__ cstd, float* __restrict__ cf) {
    const int tid = threadIdx.x;
    const int b = tid >> 6, c = tid & 63;
    __shared__ float gsm[B_][C_];
    __shared__ float hsm[B_][MID_];
    {
        const float4* p4 = (const float4*)(gp + ((size_t)b * C_ + c) * NPB_);
        float s = 0.f;
#pragma unroll 8
        for (int i = 0; i < NPB_ / 4; ++i) { float4 v = p4[i]; s += (v.x + v.y) + (v.z + v.w); }
        gsm[b][c] = s * (1.f / HW_);
    }
    __syncthreads();
    if (tid < B_ * MID_) {
        int b2 = tid / MID_, m = tid % MID_;
        float a = cb1[m];
        for (int cc = 0; cc < C_; ++cc) a = fmaf(gsm[b2][cc], cw1[m * C_ + cc], a);
        hsm[b2][m] = fmaxf(a, 0.f);
    }
    __syncthreads();
    float v[9];
    float mean = 0.f;
#pragma unroll
    for (int t = 0; t < 9; ++t) {
        int o = c * 9 + t;
        float a = cb2[o];
#pragma unroll
        for (int m = 0; m < MID_; ++m) a = fmaf(hsm[b][m], cw2[o * MID_ + m], a);
        v[t] = a;
        mean += a;
    }
    mean *= (1.f / 9.f);
    float var = 0.f;
#pragma unroll
    for (int t = 0; t < 9; ++t) { float d = v[t] - mean; var += d * d; }
    float inv = 1.f / (sqrtf(var * (1.f / 8.f)) + 1e-10f);
    float* o12 = cf + ((size_t)b * C_ + c) * 12;
#pragma unroll
    for (int t = 0; t < 9; ++t) o12[t] = (v[t] - mean) * inv * cstd[c * 9 + t];
    o12[9] = 0.f; o12[10] = 0.f; o12[11] = 0.f;
}

// ---------- apply: channel-parallel 3x3 dynamic filter, 2 px/thread ----------
// Per channel-row: 1 float2 (mid pair) + 2 scalar edge loads cover BOTH pixels'
// taps -> 9 VMEM per channel per 2 px (half of r15). All offsets stay in-plane;
// edge masking folded into s-taps. block = 128x4 px, 8 ch; grid (2,64,B*8)=4096.
template<bool RELU, bool RESID, bool INH, bool OUTH>
__global__ __launch_bounds__(256) void apply_kernel(const void* __restrict__ in,
    const float* __restrict__ sarr, const float* __restrict__ cf,
    const float* __restrict__ resid, void* __restrict__ out) {
    const int lane = threadIdx.x & 63, wv = threadIdx.x >> 6;
    const int col0 = blockIdx.x * 128 + lane * 2;     // even
    const int row = blockIdx.y * 4 + wv;
    const int z = blockIdx.z;
    const int b = z >> 3;
    const int c0 = (z & 7) * 8;
    const int pix = row * W_ + col0;

    const bool rup = row > 0, rdn = row < H_ - 1;
    const bool cl = col0 > 0;                 // px0 has left neighbor
    const bool cr = (col0 + 1) < (W_ - 1);    // px1 has right neighbor

    // s taps for the 2 pixels; fold ALL edge masks here
    float s0a[9], s0b[9];
    {
        const float* sp = sarr + ((size_t)b * 9) * HW_ + pix;
#pragma unroll
        for (int t = 0; t < 9; ++t) {
            float2 sv = *(const float2*)(sp + (size_t)t * HW_);
            s0a[t] = sv.x; s0b[t] = sv.y;
        }
#pragma unroll
        for (int t = 0; t < 3; ++t) {
            if (!rup) { s0a[t] = 0.f; s0b[t] = 0.f; }
            if (!rdn) { s0a[t + 6] = 0.f; s0b[t + 6] = 0.f; }
        }
        if (!cl) { s0a[0] = 0.f; s0a[3] = 0.f; s0a[6] = 0.f; }
        if (!cr) { s0b[2] = 0.f; s0b[5] = 0.f; s0b[8] = 0.f; }
    }

    // per-row offsets (element units within the channel plane)
    int offM[3], offL[3], offR[3];
    {
        const int ro[3] = {rup ? -W_ : 0, 0, rdn ? W_ : 0};
#pragma unroll
        for (int dr = 0; dr < 3; ++dr) {
            offM[dr] = pix + ro[dr];
            offL[dr] = offM[dr] + (cl ? -1 : 0);
            offR[dr] = offM[dr] + (cr ? 2 : 0);
        }
    }

    const size_t cbase = ((size_t)b * C_ + c0) * HW_;
    const float* inF = (const float*)in + cbase;
    const _Float16* inH = (const _Float16*)in + cbase;
    const float* cfb = cf + ((size_t)b * C_ + c0) * 12;
    const float* rb  = RESID ? ((const float*)resid + cbase + pix) : nullptr;
    float* outF = (float*)out + cbase + pix;
    _Float16* outH = (_Float16*)out + cbase + pix;

    float mA[3][2], lA[3], rA3[3];   // mid pair, left, right per row
    float mB[3][2], lB[3], rB3[3];
    float2 rvA = make_float2(0.f, 0.f), rvB = make_float2(0.f, 0.f);

#define LD(MM, LL, RR, RV, cc) do {                                          \
        if constexpr (INH) {                                                 \
            const _Float16* p_ = inH + (size_t)(cc) * HW_;                   \
            _Pragma("unroll")                                                \
            for (int dr_ = 0; dr_ < 3; ++dr_) {                              \
                h2 mv_ = *(const h2*)(p_ + offM[dr_]);                       \
                MM[dr_][0] = (float)mv_[0]; MM[dr_][1] = (float)mv_[1];      \
                LL[dr_] = (float)p_[offL[dr_]];                              \
                RR[dr_] = (float)p_[offR[dr_]];                              \
            }                                                                \
        } else {                                                             \
            const float* p_ = inF + (size_t)(cc) * HW_;                      \
            _Pragma("unroll")                                                \
            for (int dr_ = 0; dr_ < 3; ++dr_) {                              \
                float2 mv_ = *(const float2*)(p_ + offM[dr_]);               \
                MM[dr_][0] = mv_.x; MM[dr_][1] = mv_.y;                      \
                LL[dr_] = p_[offL[dr_]];                                     \
                RR[dr_] = p_[offR[dr_]];                                     \
            }                                                                \
        }                                                                    \
        if (RESID) RV = *(const float2*)(rb + (size_t)(cc) * HW_);           \
    } while (0)

#define CP(MM, LL, RR, RV, cc) do {                                         \
        const float* cfc_ = cfb + (size_t)(cc) * 12;                        \
        float a0_ = 0.f, a1_ = 0.f;                                         \
        _Pragma("unroll")                                                   \
        for (int dr_ = 0; dr_ < 3; ++dr_) {                                 \
            const int t_ = dr_ * 3;                                         \
            a0_ = fmaf(LL[dr_]    * s0a[t_],     cfc_[t_],     a0_);        \
            a0_ = fmaf(MM[dr_][0] * s0a[t_ + 1], cfc_[t_ + 1], a0_);        \
            a0_ = fmaf(MM[dr_][1] * s0a[t_ + 2], cfc_[t_ + 2], a0_);        \
            a1_ = fmaf(MM[dr_][0] * s0b[t_],     cfc_[t_],     a1_);        \
            a1_ = fmaf(MM[dr_][1] * s0b[t_ + 1], cfc_[t_ + 1], a1_);        \
            a1_ = fmaf(RR[dr_]    * s0b[t_ + 2], cfc_[t_ + 2], a1_);        \
        }                                                                   \
        if (RELU) { a0_ = fmaxf(a0_, 0.f); a1_ = fmaxf(a1_, 0.f); }         \
        if (RESID) { a0_ += RV.x; a1_ += RV.y; }                            \
        if constexpr (OUTH) {                                               \
            h2 o_; o_[0] = (_Float16)a0_; o_[1] = (_Float16)a1_;            \
            *(h2*)(outH + (size_t)(cc) * HW_) = o_;                         \
        } else {                                                            \
            *(float2*)(outF + (size_t)(cc) * HW_) = make_float2(a0_, a1_);  \
        }                                                                   \
    } while (0)

    LD(mA, lA, rA3, rvA, 0);
#pragma unroll
    for (int c = 0; c < 8; c += 2) {
        LD(mB, lB, rB3, rvB, c + 1);
        CP(mA, lA, rA3, rvA, c);
        if (c + 2 < 8) LD(mA, lA, rA3, rvA, c + 2);
        CP(mB, lB, rB3, rvB, c + 1);
    }
#undef LD
#undef CP
}

extern "C" void kernel_launch(void* const* d_in, const int* in_sizes, int n_in,
                              void* d_out, int out_size, void* d_ws, size_t ws_size,
                              hipStream_t stream) {
    const float* x     = (const float*)d_in[0];
    const float* sw1   = (const float*)d_in[1];
    const float* sb1   = (const float*)d_in[2];
    const float* sstd1 = (const float*)d_in[3];
    const float* cw1_1 = (const float*)d_in[4];
    const float* cb1_1 = (const float*)d_in[5];
    const float* cw2_1 = (const float*)d_in[6];
    const float* cb2_1 = (const float*)d_in[7];
    const float* cstd1 = (const float*)d_in[8];
    const float* sw2   = (const float*)d_in[9];
    const float* sb2   = (const float*)d_in[10];
    const float* sstd2 = (const float*)d_in[11];
    const float* cw1_2 = (const float*)d_in[12];
    const float* cb1_2 = (const float*)d_in[13];
    const float* cw2_2 = (const float*)d_in[14];
    const float* cb2_2 = (const float*)d_in[15];
    const float* cstd2 = (const float*)d_in[16];
    float* outp = (float*)d_out;

    const size_t n_out1 = (size_t)B_ * C_ * HW_;     // 16,777,216 (fp16)
    const size_t n_s    = (size_t)B_ * 9 * HW_;      // 2,359,296
    const size_t n_cf   = (size_t)B_ * C_ * 12;      // 3,072 (padded)
    const size_t n_gp   = (size_t)B_ * C_ * NPB_;    // 65,536
    const size_t need = n_out1 * sizeof(_Float16)
                      + (2 * n_s + 2 * n_cf + 2 * n_gp) * sizeof(float);
    if (ws_size < need) return;

    _Float16* out1h = (_Float16*)d_ws;
    float* s1  = (float*)((char*)d_ws + n_out1 * sizeof(_Float16));
    float* s2  = s1 + n_s;
    float* cf1 = s2 + n_s;
    float* cf2 = cf1 + n_cf;
    float* gp1 = cf2 + n_cf;
    float* gp2 = gp1 + n_gp;

    dim3 gprep(H_, B_);                     // 1024 blocks
    dim3 gapply(2, H_ / 4, B_ * 8);         // 4096 blocks, 8 ch, 2 px/thread

    // pass 1
    prep_kernel<false><<<gprep, 256, 0, stream>>>(x, sw1, sb1, sstd1, s1, gp1);
    cfk<<<1, 256, 0, stream>>>(gp1, cw1_1, cb1_1, cw2_1, cb2_1, cstd1, cf1);
    apply_kernel<true, false, false, true><<<gapply, 256, 0, stream>>>(
        x, s1, cf1, nullptr, out1h);
    // pass 2
    prep_kernel<true><<<gprep, 256, 0, stream>>>(out1h, sw2, sb2, sstd2, s2, gp2);
    cfk<<<1, 256, 0, stream>>>(gp2, cw1_2, cb1_2, cw2_2, cb2_2, cstd2, cf2);
    apply_kernel<false, true, true, false><<<gapply, 256, 0, stream>>>(
        out1h, s2, cf2, x, outp);
}

// Round 20
// 140.212 us; speedup vs baseline: 1.6395x; 1.1582x over previous
//
#include <hip/hip_runtime.h>

#define B_ 4
#define C_ 64
#define H_ 256
#define W_ 256
#define HW_ (H_*W_)
#define MID_ 12
#define NPB_ 256   // gap partial slots per image (= one per row)

typedef _Float16 h4 __attribute__((ext_vector_type(4)));

__device__ __forceinline__ float wave_reduce64(float v) {
#pragma unroll
    for (int off = 32; off; off >>= 1) v += __shfl_xor(v, off, 64);
    return v;
}

// FilterNorm over 9 taps (float4 over 4 px); writes PIXEL-MAJOR [px][12]
__device__ __forceinline__ void fnorm4_store_pm(const float4* t9,
    const float* __restrict__ sstd, float* sp /* = sarr + (b*HW+pix)*12 */) {
    float4 mean = make_float4(0, 0, 0, 0);
#pragma unroll
    for (int t = 0; t < 9; ++t) {
        mean.x += t9[t].x; mean.y += t9[t].y; mean.z += t9[t].z; mean.w += t9[t].w;
    }
    mean.x *= (1.f/9.f); mean.y *= (1.f/9.f); mean.z *= (1.f/9.f); mean.w *= (1.f/9.f);
    float4 var = make_float4(0, 0, 0, 0);
#pragma unroll
    for (int t = 0; t < 9; ++t) {
        float dx = t9[t].x - mean.x, dy = t9[t].y - mean.y;
        float dz = t9[t].z - mean.z, dw = t9[t].w - mean.w;
        var.x = fmaf(dx, dx, var.x); var.y = fmaf(dy, dy, var.y);
        var.z = fmaf(dz, dz, var.z); var.w = fmaf(dw, dw, var.w);
    }
    const float inv[4] = {
        1.f / (sqrtf(var.x * (1.f/8.f)) + 1e-10f),
        1.f / (sqrtf(var.y * (1.f/8.f)) + 1e-10f),
        1.f / (sqrtf(var.z * (1.f/8.f)) + 1e-10f),
        1.f / (sqrtf(var.w * (1.f/8.f)) + 1e-10f)};
    const float mn[4] = {mean.x, mean.y, mean.z, mean.w};
#pragma unroll
    for (int j = 0; j < 4; ++j) {
        float v9[9];
#pragma unroll
        for (int t = 0; t < 9; ++t) {
            float raw = (j == 0) ? t9[t].x : (j == 1) ? t9[t].y : (j == 2) ? t9[t].z : t9[t].w;
            v9[t] = (raw - mn[j]) * inv[j] * sstd[t];
        }
        float* o = sp + j * 12;
        *(float4*)(o)     = make_float4(v9[0], v9[1], v9[2], v9[3]);
        *(float4*)(o + 4) = make_float4(v9[4], v9[5], v9[6], v9[7]);
        *(float4*)(o + 8) = make_float4(v9[8], 0.f, 0.f, 0.f);
    }
}

// ---------------- prep: read in once -> s (pixel-major) + gap partials ----------------
// block = 1 row, 4 waves x 16 channels; lane = 4 px. grid (H, B). (r15 structure)
template<bool HALF>
__global__ __launch_bounds__(256) void prep_kernel(const void* __restrict__ xin,
    const float* __restrict__ sw, const float* __restrict__ sb,
    const float* __restrict__ sstd, float* __restrict__ sarr, float* __restrict__ gp) {
    const int lane = threadIdx.x & 63, wv = threadIdx.x >> 6;
    const int row = blockIdx.x;
    const int b = blockIdx.y;
    const int c0 = wv * 16;
    const int pix = row * W_ + lane * 4;
    __shared__ float4 stl[3][9][64];

    float4 st[9];
#pragma unroll
    for (int t = 0; t < 9; ++t) st[t] = make_float4(0, 0, 0, 0);

    const size_t base = (size_t)b * C_ * HW_ + pix;
    const float* xbF = (const float*)xin + base;
    const _Float16* xbH = (const _Float16*)xin + base;

#define LOAD4(DST, CC) do {                                                   \
        if constexpr (HALF) {                                                 \
            h4 v_ = *(const h4*)(xbH + (size_t)(CC) * HW_);                   \
            DST = make_float4((float)v_[0], (float)v_[1],                     \
                              (float)v_[2], (float)v_[3]);                    \
        } else {                                                              \
            DST = *(const float4*)(xbF + (size_t)(CC) * HW_);                 \
        }                                                                     \
    } while (0)

#define PREP_COMP(BUF, CC) do {                                               \
        _Pragma("unroll")                                                     \
        for (int i_ = 0; i_ < 4; ++i_) {                                      \
            const int c_ = (CC) + i_;                                         \
            float4 v_ = BUF[i_];                                              \
            _Pragma("unroll")                                                 \
            for (int t_ = 0; t_ < 9; ++t_) {                                  \
                const float wt_ = sw[t_ * C_ + c_];                           \
                st[t_].x = fmaf(v_.x, wt_, st[t_].x);                         \
                st[t_].y = fmaf(v_.y, wt_, st[t_].y);                         \
                st[t_].z = fmaf(v_.z, wt_, st[t_].z);                         \
                st[t_].w = fmaf(v_.w, wt_, st[t_].w);                         \
            }                                                                 \
            float g_ = wave_reduce64(((v_.x + v_.y) + (v_.z + v_.w)));        \
            if (lane == 0) gp[((size_t)b * C_ + c_) * NPB_ + blockIdx.x] = g_; \
        }                                                                     \
    } while (0)

    float4 vA[4], vB[4];
#pragma unroll
    for (int i = 0; i < 4; ++i) LOAD4(vA[i], c0 + i);
#pragma unroll
    for (int k = 0; k < 16; k += 8) {
#pragma unroll
        for (int i = 0; i < 4; ++i) LOAD4(vB[i], c0 + k + 4 + i);
        PREP_COMP(vA, c0 + k);
        if (k + 8 < 16) {
#pragma unroll
            for (int i = 0; i < 4; ++i) LOAD4(vA[i], c0 + k + 8 + i);
        }
        PREP_COMP(vB, c0 + k + 4);
    }
#undef LOAD4
#undef PREP_COMP

    if (wv) {
#pragma unroll
        for (int t = 0; t < 9; ++t) stl[wv - 1][t][lane] = st[t];
    }
    __syncthreads();
    if (wv == 0) {
#pragma unroll
        for (int t = 0; t < 9; ++t) {
            float bb = sb[t];
#pragma unroll
            for (int j = 0; j < 3; ++j) {
                float4 o = stl[j][t][lane];
                st[t].x += o.x; st[t].y += o.y; st[t].z += o.z; st[t].w += o.w;
            }
            st[t].x += bb; st[t].y += bb; st[t].z += bb; st[t].w += bb;
        }
        fnorm4_store_pm(st, sstd, sarr + ((size_t)b * HW_ + pix) * 12);
    }
}

// ------ cfk: reduce gap partials + SE MLP + FilterNorm -> cf (B,C,12 padded) ------
__global__ __launch_bounds__(256) void cfk(const float* __restrict__ gp,
    const float* __restrict__ cw1, const float* __restrict__ cb1,
    const float* __restrict__ cw2, const float* __restrict__ cb2,
    const float* __restrict__ cstd, float* __restrict__ cf) {
    const int tid = threadIdx.x;
    const int b = tid >> 6, c = tid & 63;
    __shared__ float gsm[B_][C_];
    __shared__ float hsm[B_][MID_];
    {
        const float4* p4 = (const float4*)(gp + ((size_t)b * C_ + c) * NPB_);
        float s = 0.f;
#pragma unroll 8
        for (int i = 0; i < NPB_ / 4; ++i) { float4 v = p4[i]; s += (v.x + v.y) + (v.z + v.w); }
        gsm[b][c] = s * (1.f / HW_);
    }
    __syncthreads();
    if (tid < B_ * MID_) {
        int b2 = tid / MID_, m = tid % MID_;
        float a = cb1[m];
        for (int cc = 0; cc < C_; ++cc) a = fmaf(gsm[b2][cc], cw1[m * C_ + cc], a);
        hsm[b2][m] = fmaxf(a, 0.f);
    }
    __syncthreads();
    float v[9];
    float mean = 0.f;
#pragma unroll
    for (int t = 0; t < 9; ++t) {
        int o = c * 9 + t;
        float a = cb2[o];
#pragma unroll
        for (int m = 0; m < MID_; ++m) a = fmaf(hsm[b][m], cw2[o * MID_ + m], a);
        v[t] = a;
        mean += a;
    }
    mean *= (1.f / 9.f);
    float var = 0.f;
#pragma unroll
    for (int t = 0; t < 9; ++t) { float d = v[t] - mean; var += d * d; }
    float inv = 1.f / (sqrtf(var * (1.f / 8.f)) + 1e-10f);
    float* o12 = cf + ((size_t)b * C_ + c) * 12;
#pragma unroll
    for (int t = 0; t < 9; ++t) o12[t] = (v[t] - mean) * inv * cstd[c * 9 + t];
    o12[9] = 0.f; o12[10] = 0.f; o12[11] = 0.f;
}

// ---------- apply: channel-parallel 3x3 dynamic filter, depth-4 pipeline ----------
// block = 64x4 px tile, 8 channels; 1 px/thread; grid (W/64, H/4, B*8) = 8192.
// s loaded as 3 float4 (pixel-major); edge masks folded into s0/off9.
template<bool RELU, bool RESID, bool INH, bool OUTH>
__global__ __launch_bounds__(256) void apply_kernel(const void* __restrict__ in,
    const float* __restrict__ sarr, const float* __restrict__ cf,
    const float* __restrict__ resid, void* __restrict__ out) {
    const int lane = threadIdx.x & 63, wv = threadIdx.x >> 6;
    const int col = blockIdx.x * 64 + lane;
    const int row = blockIdx.y * 4 + wv;
    const int z = blockIdx.z;
    const int b = z >> 3;
    const int c0 = (z & 7) * 8;
    const int pix = row * W_ + col;

    // s taps at my pixel (3 contiguous float4s); fold ALL edge masking here
    float s0[9];
    int off9[9];
    {
        const float* sp = sarr + ((size_t)b * HW_ + pix) * 12;
        float4 a = *(const float4*)(sp);
        float4 b4 = *(const float4*)(sp + 4);
        float4 c4 = *(const float4*)(sp + 8);
        s0[0] = a.x; s0[1] = a.y; s0[2] = a.z; s0[3] = a.w;
        s0[4] = b4.x; s0[5] = b4.y; s0[6] = b4.z; s0[7] = b4.w;
        s0[8] = c4.x;
#pragma unroll
        for (int dr = -1; dr <= 1; ++dr)
#pragma unroll
            for (int dc = -1; dc <= 1; ++dc) {
                const int t = (dr + 1) * 3 + (dc + 1);
                const bool ok = (row + dr >= 0) && (row + dr < H_) &&
                                (col + dc >= 0) && (col + dc < W_);
                off9[t] = ok ? (pix + dr * W_ + dc) : pix;
                if (!ok) s0[t] = 0.f;
            }
    }

    const size_t cbase = ((size_t)b * C_ + c0) * HW_;
    const float* inF = (const float*)in + cbase;
    const _Float16* inH = (const _Float16*)in + cbase;
    const float* cfb = cf + ((size_t)b * C_ + c0) * 12;
    const float* rb  = RESID ? ((const float*)resid + cbase + pix) : nullptr;
    float* outF = (float*)out + cbase + pix;
    _Float16* outH = (_Float16*)out + cbase + pix;

    float m0[9], m1[9], m2[9], m3[9];
    float rv0 = 0.f, rv1 = 0.f, rv2 = 0.f, rv3 = 0.f;

#define LD9(M, RV, cc) do {                                                  \
        if constexpr (INH) {                                                 \
            const _Float16* p_ = inH + (size_t)(cc) * HW_;                   \
            _Pragma("unroll")                                                \
            for (int t_ = 0; t_ < 9; ++t_) M[t_] = (float)p_[off9[t_]];      \
        } else {                                                             \
            const float* p_ = inF + (size_t)(cc) * HW_;                      \
            _Pragma("unroll")                                                \
            for (int t_ = 0; t_ < 9; ++t_) M[t_] = p_[off9[t_]];             \
        }                                                                    \
        if (RESID) RV = rb[(size_t)(cc) * HW_];                              \
    } while (0)

#define CP9(M, RV, cc) do {                                                  \
        const float* cfc_ = cfb + (size_t)(cc) * 12;                         \
        float acc_ = 0.f;                                                    \
        _Pragma("unroll")                                                    \
        for (int t_ = 0; t_ < 9; ++t_)                                       \
            acc_ = fmaf(M[t_] * s0[t_], cfc_[t_], acc_);                     \
        float o_ = RELU ? fmaxf(acc_, 0.f) : acc_;                           \
        if (RESID) o_ += RV;                                                 \
        if constexpr (OUTH) outH[(size_t)(cc) * HW_] = (_Float16)o_;         \
        else                outF[(size_t)(cc) * HW_] = o_;                   \
    } while (0)

    // depth-4 rotation over 8 channels
    LD9(m0, rv0, 0); LD9(m1, rv1, 1); LD9(m2, rv2, 2); LD9(m3, rv3, 3);
    CP9(m0, rv0, 0); LD9(m0, rv0, 4);
    CP9(m1, rv1, 1); LD9(m1, rv1, 5);
    CP9(m2, rv2, 2); LD9(m2, rv2, 6);
    CP9(m3, rv3, 3); LD9(m3, rv3, 7);
    CP9(m0, rv0, 4); CP9(m1, rv1, 5); CP9(m2, rv2, 6); CP9(m3, rv3, 7);
#undef LD9
#undef CP9
}

extern "C" void kernel_launch(void* const* d_in, const int* in_sizes, int n_in,
                              void* d_out, int out_size, void* d_ws, size_t ws_size,
                              hipStream_t stream) {
    const float* x     = (const float*)d_in[0];
    const float* sw1   = (const float*)d_in[1];
    const float* sb1   = (const float*)d_in[2];
    const float* sstd1 = (const float*)d_in[3];
    const float* cw1_1 = (const float*)d_in[4];
    const float* cb1_1 = (const float*)d_in[5];
    const float* cw2_1 = (const float*)d_in[6];
    const float* cb2_1 = (const float*)d_in[7];
    const float* cstd1 = (const float*)d_in[8];
    const float* sw2   = (const float*)d_in[9];
    const float* sb2   = (const float*)d_in[10];
    const float* sstd2 = (const float*)d_in[11];
    const float* cw1_2 = (const float*)d_in[12];
    const float* cb1_2 = (const float*)d_in[13];
    const float* cw2_2 = (const float*)d_in[14];
    const float* cb2_2 = (const float*)d_in[15];
    const float* cstd2 = (const float*)d_in[16];
    float* outp = (float*)d_out;

    const size_t n_out1 = (size_t)B_ * C_ * HW_;     // 16,777,216 (fp16)
    const size_t n_s    = (size_t)B_ * HW_ * 12;     // 3,145,728 (pixel-major)
    const size_t n_cf   = (size_t)B_ * C_ * 12;      // 3,072 (padded)
    const size_t n_gp   = (size_t)B_ * C_ * NPB_;    // 65,536
    const size_t need = n_out1 * sizeof(_Float16)
                      + (2 * n_s + 2 * n_cf + 2 * n_gp) * sizeof(float);
    if (ws_size < need) return;

    _Float16* out1h = (_Float16*)d_ws;
    float* s1  = (float*)((char*)d_ws + n_out1 * sizeof(_Float16));
    float* s2  = s1 + n_s;
    float* cf1 = s2 + n_s;
    float* cf2 = cf1 + n_cf;
    float* gp1 = cf2 + n_cf;
    float* gp2 = gp1 + n_gp;

    dim3 gprep(H_, B_);                     // 1024 blocks
    dim3 gapply(W_ / 64, H_ / 4, B_ * 8);   // 8192 blocks, 8 ch each

    // pass 1
    prep_kernel<false><<<gprep, 256, 0, stream>>>(x, sw1, sb1, sstd1, s1, gp1);
    cfk<<<1, 256, 0, stream>>>(gp1, cw1_1, cb1_1, cw2_1, cb2_1, cstd1, cf1);
    apply_kernel<true, false, false, true><<<gapply, 256, 0, stream>>>(
        x, s1, cf1, nullptr, out1h);
    // pass 2
    prep_kernel<true><<<gprep, 256, 0, stream>>>(out1h, sw2, sb2, sstd2, s2, gp2);
    cfk<<<1, 256, 0, stream>>>(gp2, cw1_2, cb1_2, cw2_2, cb2_2, cstd2, cf2);
    apply_kernel<false, true, true, false><<<gapply, 256, 0, stream>>>(
        out1h, s2, cf2, x, outp);
}